// Round 4
// baseline (246.616 us; speedup 1.0000x reference)
//
#include <hip/hip_runtime.h>

#define NC   8
#define MTOT 17408   // NSPOKE*NVEC = 34*512

typedef __attribute__((ext_vector_type(8)))  short short8;
typedef __attribute__((ext_vector_type(16))) float f32x16;

typedef __attribute__((address_space(3))) unsigned       lds_uint;
typedef const __attribute__((address_space(1))) unsigned glb_uint;

static __device__ __forceinline__ short f2bf(float f) {
    union { float f; unsigned u; } v; v.f = f;
    return (short)((v.u + 0x7fffu + ((v.u >> 16) & 1u)) >> 16);
}

// Fused prep. Blocks [0,2048): src planes  src[c][a][b] = (X*C) -> Sr, Si.
// Blocks [2048,4224): Eb table in 32x32x16 B-fragment order:
//   EbT[((kt*32 + plane*16 + ks))*512 + lane*8 + j]
//     = exp(-i * t_k * b'), k = kt*32 + (lane&31), b' = ks*16+(lane>>5)*8+j-128.
__global__ __launch_bounds__(256) void prep(
        const float* __restrict__ X, const float* __restrict__ C,
        const float* __restrict__ angles,
        short* __restrict__ Sr, short* __restrict__ Si,
        short* __restrict__ EbT) {
    int bx = blockIdx.x;
    if (bx < 2048) {
        int idx = bx * 256 + threadIdx.x;   // [0, 8*65536)
        int ab = idx & 65535;
        float xr = X[ab * 2 + 0], xi = X[ab * 2 + 1];
        float cr = C[idx * 2 + 0], ci = C[idx * 2 + 1];
        Sr[idx] = f2bf(xr * cr - xi * ci);
        Si[idx] = f2bf(xr * ci + xi * cr);
    } else {
        int gid  = (bx - 2048) * 256 + threadIdx.x;  // [0, 544*1024)
        int kt   = gid >> 10;
        int r    = gid & 1023;
        int ks   = r >> 6;
        int lane = r & 63;
        int k    = kt * 32 + (lane & 31);
        float t  = angles[k * 2 + 1];
        short8 re, im;
        #pragma unroll
        for (int j = 0; j < 8; ++j) {
            float xb = (float)(ks * 16 + (lane >> 5) * 8 + j - 128);
            float sn, cs;
            __sincosf(t * xb, &sn, &cs);
            re[j] = f2bf(cs);
            im[j] = f2bf(-sn);
        }
        short* base = EbT + (size_t)(kt * 32 + ks) * 512 + lane * 8;
        *(short8*)(base)        = re;
        *(short8*)(base + 8192) = im;   // plane stride within kt block = 16*512
    }
}

// Main: y[c,k] = w[k] * sum_a Ea[k,a] * sum_b src[c,a,b] * Eb[k,b]
// Block = 4 waves x 32 k-cols = 128 k, one coil. mfma_f32_32x32x16_bf16.
// Single 32KB LDS A-tile (32 a-rows x 256 b x 2 planes), staged per at-iter
// via global_load_lds (pre-swizzled source, slot = chunk^(row&7), rule #21).
// Occupancy is the point: 32KB LDS + 128 VGPR -> 4 blocks/CU (16 waves/CU);
// cross-block TLP hides the intra-block stage->barrier->compute serialization.
template<int USE_TABLE>
__global__ __launch_bounds__(256, 4) void nufft_fwd(
        const float* __restrict__ angles, const float* __restrict__ w,
        const short* __restrict__ SrP, const short* __restrict__ SiP,
        const short* __restrict__ EbT, float* __restrict__ out) {
    __shared__ char lds[32768];

    const int tid  = threadIdx.x;
    const int lane = tid & 63;
    const int wv   = tid >> 6;
    const int c    = blockIdx.y;
    const int col  = lane & 31;      // MFMA: A-row / B-col / D-col
    const int hi   = lane >> 5;      // MFMA: K-half selector
    const int kt   = blockIdx.x * 4 + wv;
    const int k    = kt * 32 + col;
    const float s  = angles[k * 2 + 0];

    const short* Sr = SrP + c * 65536;
    const short* Si = SiP + c * 65536;
    const short* tb = EbT + (size_t)(kt * 32) * 512 + lane * 8;
    const float  t  = USE_TABLE ? 0.f : angles[k * 2 + 1];

    // Stage a-tile `at` (32 rows x 256 b x 2 planes = 2048 x 16B chunks).
    // Linear LDS dest (wave-uniform base + lane*16); source chunk pre-swizzled.
    auto stage = [&](int at) {
        #pragma unroll
        for (int it = 0; it < 8; ++it) {
            int L   = it * 256 + tid;          // linear 16B-chunk id
            int row = (L >> 5) & 31;
            int cb  = (L & 31) ^ (row & 7);    // global chunk for this slot
            const short* g = ((L >> 10) ? Si : Sr) + (at * 32 + row) * 256 + cb * 8;
            __builtin_amdgcn_global_load_lds(
                (glb_uint*)g,
                (lds_uint*)(lds + (it * 256 + (tid & ~63)) * 16),
                16, 0, 0);
        }
    };

    float yr = 0.f, yi = 0.f;

    for (int at = 0; at < 8; ++at) {
        stage(at);
        __syncthreads();                 // compiler drains vmcnt before barrier

        f32x16 P1 = {0.f}, P2 = {0.f}, P3 = {0.f}, P4 = {0.f};
        const int rowoff = col * 512;
        const int swz    = col & 7;
        __builtin_amdgcn_s_setprio(1);
        #pragma unroll
        for (int ks = 0; ks < 16; ++ks) {
            // B fragments streamed per-ks (L2-resident table; keeps VGPR <=128
            // so 4 blocks/CU — a 128-reg resident array would force scratch).
            short8 Brk, Bik;
            if constexpr (USE_TABLE) {
                Brk = *(const short8*)(tb + ks * 512);
                Bik = *(const short8*)(tb + 8192 + ks * 512);
            } else {
                #pragma unroll
                for (int j = 0; j < 8; ++j) {
                    float xb = (float)(ks * 16 + hi * 8 + j - 128);
                    float sn, cs;
                    __sincosf(t * xb, &sn, &cs);
                    Brk[j] = f2bf(cs);
                    Bik[j] = f2bf(-sn);
                }
            }
            int slot = ((ks * 2 + hi) ^ swz) << 4;
            short8 Arf = *(const short8*)(lds + rowoff + slot);
            short8 Aif = *(const short8*)(lds + 16384 + rowoff + slot);
            P1 = __builtin_amdgcn_mfma_f32_32x32x16_bf16(Arf, Brk, P1, 0, 0, 0);
            P2 = __builtin_amdgcn_mfma_f32_32x32x16_bf16(Aif, Bik, P2, 0, 0, 0);
            P3 = __builtin_amdgcn_mfma_f32_32x32x16_bf16(Arf, Bik, P3, 0, 0, 0);
            P4 = __builtin_amdgcn_mfma_f32_32x32x16_bf16(Aif, Brk, P4, 0, 0, 0);
        }
        __builtin_amdgcn_s_setprio(0);

        // Epilogue: D col = lane&31 (k), row = (reg&3)+8*(reg>>2)+4*hi (a).
        #pragma unroll
        for (int reg = 0; reg < 16; ++reg) {
            int ap = at * 32 + (reg & 3) + 8 * (reg >> 2) + 4 * hi - 128;
            float Tr = P1[reg] - P2[reg];
            float Ti = P3[reg] + P4[reg];
            float sn, cs;
            __sincosf(s * (float)ap, &sn, &cs);
            yr += cs * Tr + sn * Ti;   // Ea = cs - i*sn
            yi += cs * Ti - sn * Tr;
        }
        __syncthreads();               // all waves done reading -> next stage
    }

    // Lanes l and l+32 hold disjoint a-rows of the same k-col.
    yr += __shfl_xor(yr, 32);
    yi += __shfl_xor(yi, 32);

    if (hi == 0) {
        float wk = w[k];
        out[((size_t)c * MTOT + k) * 2 + 0] = yr * wk;
        out[((size_t)c * MTOT + k) * 2 + 1] = yi * wk;
    }
}

extern "C" void kernel_launch(void* const* d_in, const int* in_sizes, int n_in,
                              void* d_out, int out_size, void* d_ws, size_t ws_size,
                              hipStream_t stream) {
    const float* X      = (const float*)d_in[0];
    const float* angles = (const float*)d_in[1];
    const float* C      = (const float*)d_in[2];
    const float* w      = (const float*)d_in[3];
    float* out = (float*)d_out;

    short* Sr  = (short*)d_ws;           // 1 MB
    short* Si  = Sr + NC * 65536;        // 1 MB
    short* EbT = Si + NC * 65536;        // 17.8 MB (fragment-order Eb table)

    size_t need = ((size_t)NC * 65536 * 2 + (size_t)MTOT * 512) * sizeof(short);
    const bool use_table = ws_size >= need;

    dim3 grid(MTOT / 128, NC);           // (136, 8)
    if (use_table) {
        prep<<<dim3(2048 + MTOT * 32 / 256), dim3(256), 0, stream>>>(
            X, C, angles, Sr, Si, EbT);
        nufft_fwd<1><<<grid, dim3(256), 0, stream>>>(angles, w, Sr, Si, EbT, out);
    } else {
        prep<<<dim3(2048), dim3(256), 0, stream>>>(X, C, angles, Sr, Si, EbT);
        nufft_fwd<0><<<grid, dim3(256), 0, stream>>>(angles, w, Sr, Si, nullptr, out);
    }
}

// Round 5
// 190.139 us; speedup vs baseline: 1.2970x; 1.2970x over previous
//
#include <hip/hip_runtime.h>

#define NC   8
#define MTOT 17408   // NSPOKE*NVEC = 34*512

typedef __attribute__((ext_vector_type(8)))  short short8;
typedef __attribute__((ext_vector_type(16))) float f32x16;

typedef __attribute__((address_space(3))) unsigned       lds_uint;
typedef const __attribute__((address_space(1))) unsigned glb_uint;

static __device__ __forceinline__ short f2bf(float f) {
    union { float f; unsigned u; } v; v.f = f;
    return (short)((v.u + 0x7fffu + ((v.u >> 16) & 1u)) >> 16);
}

// Fused prep. Blocks [0,2048): src planes  src[c][a][b] = (X*C) -> Sr, Si.
// Blocks [2048,4224): Eb table in 32x32x16 B-fragment order:
//   Br[kt][ks] at EbT[(kt*32+ks)*512 + lane*8 + j], Bi at +8192 within kt blk:
//   exp(-i*t_k*b'), k = kt*32+(lane&31), b' = ks*16+(lane>>5)*8+j-128.
__global__ __launch_bounds__(256) void prep(
        const float* __restrict__ X, const float* __restrict__ C,
        const float* __restrict__ angles,
        short* __restrict__ Sr, short* __restrict__ Si,
        short* __restrict__ EbT) {
    int bx = blockIdx.x;
    if (bx < 2048) {
        int idx = bx * 256 + threadIdx.x;   // [0, 8*65536)
        int ab = idx & 65535;
        float xr = X[ab * 2 + 0], xi = X[ab * 2 + 1];
        float cr = C[idx * 2 + 0], ci = C[idx * 2 + 1];
        Sr[idx] = f2bf(xr * cr - xi * ci);
        Si[idx] = f2bf(xr * ci + xi * cr);
    } else {
        int gid  = (bx - 2048) * 256 + threadIdx.x;  // [0, 544*1024)
        int kt   = gid >> 10;
        int r    = gid & 1023;
        int ks   = r >> 6;
        int lane = r & 63;
        int k    = kt * 32 + (lane & 31);
        float t  = angles[k * 2 + 1];
        short8 re, im;
        #pragma unroll
        for (int j = 0; j < 8; ++j) {
            float xb = (float)(ks * 16 + (lane >> 5) * 8 + j - 128);
            float sn, cs;
            __sincosf(t * xb, &sn, &cs);
            re[j] = f2bf(cs);
            im[j] = f2bf(-sn);
        }
        short* base = EbT + (size_t)(kt * 32 + ks) * 512 + lane * 8;
        *(short8*)(base)        = re;
        *(short8*)(base + 8192) = im;
    }
}

// Main: y[c,k] = w[k] * sum_a Ea[k,a] * sum_b src[c,a,b] * Eb[k,b]
// R3 structure (4 waves x 32 k, 32-row a-tiles, 64KB dbuf LDS) + phase-split
// schedule: 4 phases/at-iter {B-loads, stage-issue(at+1), ds_reads, s_barrier,
// setprio+16 MFMA}, single vmcnt(0) at tile boundary (loads issued one full
// at-iter earlier -> drain ~free). Epilogue via fp32 phasor rotation (no
// in-loop sincos). Grid 1-D 1088; coil = bid&7 pins each coil to one XCD.
template<int USE_TABLE>
__global__ __launch_bounds__(256, 2) void nufft_fwd(
        const float* __restrict__ angles, const float* __restrict__ w,
        const short* __restrict__ SrP, const short* __restrict__ SiP,
        const short* __restrict__ EbT, float* __restrict__ out) {
    __shared__ char lds[65536];

    const int tid  = threadIdx.x;
    const int lane = tid & 63;
    const int wv   = tid >> 6;
    const int c    = blockIdx.x & 7;        // coil == XCD (round-robin)
    const int bx   = blockIdx.x >> 3;       // k-tile group [0,136)
    const int col  = lane & 31;             // MFMA: A-row / B-col / D-col
    const int hi   = lane >> 5;             // MFMA: K-half selector
    const int kt   = bx * 4 + wv;
    const int k    = kt * 32 + col;
    const float s  = angles[k * 2 + 0];

    const short* Sr = SrP + c * 65536;
    const short* Si = SiP + c * 65536;
    const short* tb = EbT + (size_t)kt * 16384 + lane * 8;
    const float  t  = USE_TABLE ? 0.f : angles[k * 2 + 1];

    // Phasors p[r] = exp(-i*s*a), a = r + 4*hi - 128; rotate by exp(-i*8s)
    // once per quad (4 quads/at-iter, 32 steps total -> seamless a-walk).
    float pR[4], pI[4], r8R, r8I;
    #pragma unroll
    for (int r = 0; r < 4; ++r) {
        float sn, cs;
        __sincosf(s * (float)(r + 4 * hi - 128), &sn, &cs);
        pR[r] = cs; pI[r] = -sn;
    }
    { float sn, cs; __sincosf(8.f * s, &sn, &cs); r8R = cs; r8I = -sn; }

    // Stage 2 of the 8 per-thread chunks of a-tile `at` into LDS half.
    // Linear LDS dest (wave base + lane*16); source chunk pre-swizzled
    // (slot = chunk ^ (row&7), rule #21).
    auto stage2 = [&](int at, int half, int ph) {
        #pragma unroll
        for (int u = 0; u < 2; ++u) {
            int it  = ph * 2 + u;
            int L   = it * 256 + tid;          // linear 16B-chunk id [0,2048)
            int row = (L >> 5) & 31;
            int cb  = (L & 31) ^ (row & 7);
            const short* g = ((L >> 10) ? Si : Sr) + (at * 32 + row) * 256 + cb * 8;
            __builtin_amdgcn_global_load_lds(
                (glb_uint*)g,
                (lds_uint*)(lds + half * 32768 + (it * 256 + (tid & ~63)) * 16),
                16, 0, 0);
        }
    };

    float yr = 0.f, yi = 0.f;
    const int rowoff = col * 512;
    const int swz    = col & 7;

    // Prologue: stage tile 0 fully.
    #pragma unroll
    for (int ph = 0; ph < 4; ++ph) stage2(0, 0, ph);

    for (int at = 0; at < 8; ++at) {
        const int cur = at & 1;
        // Own stage-writes for buf[cur] done; barrier makes all waves' done.
        asm volatile("s_waitcnt vmcnt(0)" ::: "memory");
        __builtin_amdgcn_s_barrier();

        const char* buf = lds + cur * 32768;
        f32x16 P1 = {0.f}, P2 = {0.f}, P3 = {0.f}, P4 = {0.f};

        #pragma unroll
        for (int ph = 0; ph < 4; ++ph) {
            // B fragments for this phase's 4 K-steps (L2 stream or sincos).
            short8 Brf[4], Bif[4];
            if constexpr (USE_TABLE) {
                #pragma unroll
                for (int u = 0; u < 4; ++u) {
                    Brf[u] = *(const short8*)(tb + (ph * 4 + u) * 512);
                    Bif[u] = *(const short8*)(tb + 8192 + (ph * 4 + u) * 512);
                }
            } else {
                #pragma unroll
                for (int u = 0; u < 4; ++u) {
                    #pragma unroll
                    for (int j = 0; j < 8; ++j) {
                        float xb = (float)((ph * 4 + u) * 16 + hi * 8 + j - 128);
                        float sn, cs;
                        __sincosf(t * xb, &sn, &cs);
                        Brf[u][j] = f2bf(cs);
                        Bif[u][j] = f2bf(-sn);
                    }
                }
            }
            // Issue next-tile staging (targets buf[cur^1]; no wait here).
            if (at < 7) stage2(at + 1, cur ^ 1, ph);
            // A fragments for this phase.
            short8 Arf[4], Aif[4];
            #pragma unroll
            for (int u = 0; u < 4; ++u) {
                int slot = (((ph * 4 + u) * 2 + hi) ^ swz) << 4;
                Arf[u] = *(const short8*)(buf + rowoff + slot);
                Aif[u] = *(const short8*)(buf + 16384 + rowoff + slot);
            }
            // Align waves, then a pure-MFMA cluster (compiler inserts the
            // fine-grained lgkm/vm waits for Arf/Brf deps).
            __builtin_amdgcn_s_barrier();
            __builtin_amdgcn_s_setprio(1);
            #pragma unroll
            for (int u = 0; u < 4; ++u) {
                P1 = __builtin_amdgcn_mfma_f32_32x32x16_bf16(Arf[u], Brf[u], P1, 0, 0, 0);
                P2 = __builtin_amdgcn_mfma_f32_32x32x16_bf16(Aif[u], Bif[u], P2, 0, 0, 0);
                P3 = __builtin_amdgcn_mfma_f32_32x32x16_bf16(Arf[u], Bif[u], P3, 0, 0, 0);
                P4 = __builtin_amdgcn_mfma_f32_32x32x16_bf16(Aif[u], Brf[u], P4, 0, 0, 0);
            }
            __builtin_amdgcn_s_setprio(0);
        }

        // Epilogue: D col = lane&31 (k), row a = (reg&3)+8*(reg>>2)+4*hi.
        // y += p * T with p = exp(-i*s*a) maintained by rotation.
        #pragma unroll
        for (int q = 0; q < 4; ++q) {
            #pragma unroll
            for (int r = 0; r < 4; ++r) {
                int reg = q * 4 + r;
                float Tr = P1[reg] - P2[reg];
                float Ti = P3[reg] + P4[reg];
                yr += pR[r] * Tr - pI[r] * Ti;
                yi += pR[r] * Ti + pI[r] * Tr;
            }
            #pragma unroll
            for (int r = 0; r < 4; ++r) {   // p[r] *= exp(-i*8s)
                float nR = pR[r] * r8R - pI[r] * r8I;
                float nI = pR[r] * r8I + pI[r] * r8R;
                pR[r] = nR; pI[r] = nI;
            }
        }
    }

    // Lanes l and l+32 hold disjoint a-rows of the same k-col.
    yr += __shfl_xor(yr, 32);
    yi += __shfl_xor(yi, 32);

    if (hi == 0) {
        float wk = w[k];
        out[((size_t)c * MTOT + k) * 2 + 0] = yr * wk;
        out[((size_t)c * MTOT + k) * 2 + 1] = yi * wk;
    }
}

extern "C" void kernel_launch(void* const* d_in, const int* in_sizes, int n_in,
                              void* d_out, int out_size, void* d_ws, size_t ws_size,
                              hipStream_t stream) {
    const float* X      = (const float*)d_in[0];
    const float* angles = (const float*)d_in[1];
    const float* C      = (const float*)d_in[2];
    const float* w      = (const float*)d_in[3];
    float* out = (float*)d_out;

    short* Sr  = (short*)d_ws;           // 1 MB
    short* Si  = Sr + NC * 65536;        // 1 MB
    short* EbT = Si + NC * 65536;        // 17.8 MB (fragment-order Eb table)

    size_t need = ((size_t)NC * 65536 * 2 + (size_t)MTOT * 512) * sizeof(short);
    const bool use_table = ws_size >= need;

    dim3 grid(MTOT / 128 * NC);          // 1088, 1-D; coil = bid&7 (XCD-pinned)
    if (use_table) {
        prep<<<dim3(2048 + MTOT * 32 / 256), dim3(256), 0, stream>>>(
            X, C, angles, Sr, Si, EbT);
        nufft_fwd<1><<<grid, dim3(256), 0, stream>>>(angles, w, Sr, Si, EbT, out);
    } else {
        prep<<<dim3(2048), dim3(256), 0, stream>>>(X, C, angles, Sr, Si, EbT);
        nufft_fwd<0><<<grid, dim3(256), 0, stream>>>(angles, w, Sr, Si, nullptr, out);
    }
}

// Round 6
// 101.784 us; speedup vs baseline: 2.4229x; 1.8681x over previous
//
#include <hip/hip_runtime.h>

#define NC   8
#define MTOT 17408   // NSPOKE*NVEC = 34*512

typedef __attribute__((ext_vector_type(8)))  short short8;
typedef __attribute__((ext_vector_type(16))) float f32x16;

typedef __attribute__((address_space(3))) unsigned       lds_uint;
typedef const __attribute__((address_space(1))) unsigned glb_uint;

static __device__ __forceinline__ short f2bf(float f) {
    union { float f; unsigned u; } v; v.f = f;
    return (short)((v.u + 0x7fffu + ((v.u >> 16) & 1u)) >> 16);
}

// Pin a 128-bit fragment in VGPRs: asm results are not rematerializable,
// so the allocator cannot "re-load from global" instead of keeping it.
static __device__ __forceinline__ void pin(short8& v) {
    asm volatile("" : "+v"(v));
}

// Fused prep. Blocks [0,2048): src planes  src[c][a][b] = (X*C) -> Sr, Si.
// Blocks [2048,4224): Eb table in 32x32x16 B-fragment order:
//   Br[kt][ks] at EbT[(kt*32+ks)*512 + lane*8 + j], Bi at +8192 within kt blk:
//   exp(-i*t_k*b'), k = kt*32+(lane&31), b' = ks*16+(lane>>5)*8+j-128.
__global__ __launch_bounds__(256) void prep(
        const float* __restrict__ X, const float* __restrict__ C,
        const float* __restrict__ angles,
        short* __restrict__ Sr, short* __restrict__ Si,
        short* __restrict__ EbT) {
    int bx = blockIdx.x;
    if (bx < 2048) {
        int idx = bx * 256 + threadIdx.x;   // [0, 8*65536)
        int ab = idx & 65535;
        float xr = X[ab * 2 + 0], xi = X[ab * 2 + 1];
        float cr = C[idx * 2 + 0], ci = C[idx * 2 + 1];
        Sr[idx] = f2bf(xr * cr - xi * ci);
        Si[idx] = f2bf(xr * ci + xi * cr);
    } else {
        int gid  = (bx - 2048) * 256 + threadIdx.x;  // [0, 544*1024)
        int kt   = gid >> 10;
        int r    = gid & 1023;
        int ks   = r >> 6;
        int lane = r & 63;
        int k    = kt * 32 + (lane & 31);
        float t  = angles[k * 2 + 1];
        short8 re, im;
        #pragma unroll
        for (int j = 0; j < 8; ++j) {
            float xb = (float)(ks * 16 + (lane >> 5) * 8 + j - 128);
            float sn, cs;
            __sincosf(t * xb, &sn, &cs);
            re[j] = f2bf(cs);
            im[j] = f2bf(-sn);
        }
        short* base = EbT + (size_t)(kt * 32 + ks) * 512 + lane * 8;
        *(short8*)(base)        = re;
        *(short8*)(base + 8192) = im;
    }
}

// Main: y[c,k] = w[k] * sum_a Ea[k,a] * sum_b src[c,a,b] * Eb[k,b]
// Grid (136, 8) natural order: XCD = bx%8 (136%8==0), so the 8 coil-blocks
// sharing one EbT slice co-reside on an XCD (EbT/XCD ~0.5MB + src 2MB -> L2).
// 4 waves x 32 k, 32-row a-tiles, 64KB dbuf LDS via global_load_lds
// (pre-swizzled source, slot = chunk^(row&7), rule #21).
// B fragments loaded ONCE, pinned in 128 VGPRs. Phase-split schedule:
// per at-iter 4 phases {stage-issue, barrier, setprio + ds_read/MFMA cluster};
// single vmcnt(0) at tile boundary. Epilogue: fp32 phasor rotation.
template<int USE_TABLE>
__global__ __launch_bounds__(256, 2) void nufft_fwd(
        const float* __restrict__ angles, const float* __restrict__ w,
        const short* __restrict__ SrP, const short* __restrict__ SiP,
        const short* __restrict__ EbT, float* __restrict__ out) {
    __shared__ char lds[65536];

    const int tid  = threadIdx.x;
    const int lane = tid & 63;
    const int wv   = tid >> 6;
    const int c    = blockIdx.y;            // coil
    const int bx   = blockIdx.x;            // k-tile group [0,136)
    const int col  = lane & 31;             // MFMA: A-row / B-col / D-col
    const int hi   = lane >> 5;             // MFMA: K-half selector
    const int kt   = bx * 4 + wv;
    const int k    = kt * 32 + col;
    const float s  = angles[k * 2 + 0];

    const short* Sr = SrP + c * 65536;
    const short* Si = SiP + c * 65536;
    const short* tb = EbT + (size_t)kt * 16384 + lane * 8;

    // Phasors p[r] = exp(-i*s*a), a = r + 4*hi - 128; rotated by exp(-i*8s)
    // per quad (4 quads/at-iter, 32 a-steps total -> seamless walk).
    float pR[4], pI[4], r8R, r8I;
    #pragma unroll
    for (int r = 0; r < 4; ++r) {
        float sn, cs;
        __sincosf(s * (float)(r + 4 * hi - 128), &sn, &cs);
        pR[r] = cs; pI[r] = -sn;
    }
    { float sn, cs; __sincosf(8.f * s, &sn, &cs); r8R = cs; r8I = -sn; }

    // Stage 2 of the 8 per-thread chunk-groups of a-tile `at` into LDS half.
    // Linear LDS dest (wave base + lane*16); source chunk pre-swizzled.
    auto stage2 = [&](int at, int half, int ph) {
        #pragma unroll
        for (int u = 0; u < 2; ++u) {
            int it  = ph * 2 + u;
            int L   = it * 256 + tid;          // linear 16B-chunk id [0,2048)
            int row = (L >> 5) & 31;
            int cb  = (L & 31) ^ (row & 7);
            const short* g = ((L >> 10) ? Si : Sr) + (at * 32 + row) * 256 + cb * 8;
            __builtin_amdgcn_global_load_lds(
                (glb_uint*)g,
                (lds_uint*)(lds + half * 32768 + (it * 256 + (tid & ~63)) * 16),
                16, 0, 0);
        }
    };

    // Prologue: stage tile 0, then load B fragments once and pin them.
    #pragma unroll
    for (int ph = 0; ph < 4; ++ph) stage2(0, 0, ph);

    short8 Br[16], Bi[16];
    if constexpr (USE_TABLE) {
        #pragma unroll
        for (int ks = 0; ks < 16; ++ks) {
            Br[ks] = *(const short8*)(tb + ks * 512);
            Bi[ks] = *(const short8*)(tb + 8192 + ks * 512);
        }
    } else {
        const float t = angles[k * 2 + 1];
        #pragma unroll
        for (int ks = 0; ks < 16; ++ks) {
            #pragma unroll
            for (int j = 0; j < 8; ++j) {
                float xb = (float)(ks * 16 + hi * 8 + j - 128);
                float sn, cs;
                __sincosf(t * xb, &sn, &cs);
                Br[ks][j] = f2bf(cs);
                Bi[ks][j] = f2bf(-sn);
            }
        }
    }
    #pragma unroll
    for (int ks = 0; ks < 16; ++ks) { pin(Br[ks]); pin(Bi[ks]); }

    float yr = 0.f, yi = 0.f;
    const int rowoff = col * 512;
    const int swz    = col & 7;

    for (int at = 0; at < 8; ++at) {
        const int cur = at & 1;
        // Own stage-writes (and prologue B loads on iter 0) drained; barrier
        // makes all waves' writes to buf[cur] visible.
        asm volatile("s_waitcnt vmcnt(0)" ::: "memory");
        __builtin_amdgcn_s_barrier();

        const char* buf = lds + cur * 32768;
        f32x16 P1 = {0.f}, P2 = {0.f}, P3 = {0.f}, P4 = {0.f};

        #pragma unroll
        for (int ph = 0; ph < 4; ++ph) {
            // Issue next-tile staging (targets buf[cur^1]; no wait here).
            if (at < 7) stage2(at + 1, cur ^ 1, ph);
            // Align waves, then ds_read + MFMA cluster (compiler inserts
            // fine-grained lgkmcnt between ds_read and dependent MFMA).
            __builtin_amdgcn_s_barrier();
            __builtin_amdgcn_s_setprio(1);
            #pragma unroll
            for (int u = 0; u < 4; ++u) {
                const int ks = ph * 4 + u;
                int slot = ((ks * 2 + hi) ^ swz) << 4;
                short8 Arf = *(const short8*)(buf + rowoff + slot);
                short8 Aif = *(const short8*)(buf + 16384 + rowoff + slot);
                P1 = __builtin_amdgcn_mfma_f32_32x32x16_bf16(Arf, Br[ks], P1, 0, 0, 0);
                P2 = __builtin_amdgcn_mfma_f32_32x32x16_bf16(Aif, Bi[ks], P2, 0, 0, 0);
                P3 = __builtin_amdgcn_mfma_f32_32x32x16_bf16(Arf, Bi[ks], P3, 0, 0, 0);
                P4 = __builtin_amdgcn_mfma_f32_32x32x16_bf16(Aif, Br[ks], P4, 0, 0, 0);
            }
            __builtin_amdgcn_s_setprio(0);
        }

        // Epilogue: D col = lane&31 (k), row a = (reg&3)+8*(reg>>2)+4*hi.
        // y += conj-phase * T with p = exp(-i*s*a) maintained by rotation.
        #pragma unroll
        for (int q = 0; q < 4; ++q) {
            #pragma unroll
            for (int r = 0; r < 4; ++r) {
                int reg = q * 4 + r;
                float Tr = P1[reg] - P2[reg];
                float Ti = P3[reg] + P4[reg];
                yr += pR[r] * Tr - pI[r] * Ti;
                yi += pR[r] * Ti + pI[r] * Tr;
            }
            #pragma unroll
            for (int r = 0; r < 4; ++r) {   // p[r] *= exp(-i*8s)
                float nR = pR[r] * r8R - pI[r] * r8I;
                float nI = pR[r] * r8I + pI[r] * r8R;
                pR[r] = nR; pI[r] = nI;
            }
        }
    }

    // Lanes l and l+32 hold disjoint a-rows of the same k-col.
    yr += __shfl_xor(yr, 32);
    yi += __shfl_xor(yi, 32);

    if (hi == 0) {
        float wk = w[k];
        out[((size_t)c * MTOT + k) * 2 + 0] = yr * wk;
        out[((size_t)c * MTOT + k) * 2 + 1] = yi * wk;
    }
}

extern "C" void kernel_launch(void* const* d_in, const int* in_sizes, int n_in,
                              void* d_out, int out_size, void* d_ws, size_t ws_size,
                              hipStream_t stream) {
    const float* X      = (const float*)d_in[0];
    const float* angles = (const float*)d_in[1];
    const float* C      = (const float*)d_in[2];
    const float* w      = (const float*)d_in[3];
    float* out = (float*)d_out;

    short* Sr  = (short*)d_ws;           // 1 MB
    short* Si  = Sr + NC * 65536;        // 1 MB
    short* EbT = Si + NC * 65536;        // 17.8 MB (fragment-order Eb table)

    size_t need = ((size_t)NC * 65536 * 2 + (size_t)MTOT * 512) * sizeof(short);
    const bool use_table = ws_size >= need;

    // 2-D grid, natural dispatch: bid = y*136 + x, 136%8==0 -> XCD = x%8.
    // Coil-blocks sharing an EbT slice (same x) land on the same XCD.
    dim3 grid(MTOT / 128, NC);           // (136, 8)
    if (use_table) {
        prep<<<dim3(2048 + MTOT * 32 / 256), dim3(256), 0, stream>>>(
            X, C, angles, Sr, Si, EbT);
        nufft_fwd<1><<<grid, dim3(256), 0, stream>>>(angles, w, Sr, Si, EbT, out);
    } else {
        prep<<<dim3(2048), dim3(256), 0, stream>>>(X, C, angles, Sr, Si, EbT);
        nufft_fwd<0><<<grid, dim3(256), 0, stream>>>(angles, w, Sr, Si, nullptr, out);
    }
}